// Round 11
// baseline (1074.794 us; speedup 1.0000x reference)
//
#include <hip/hip_runtime.h>

// Problem constants
constexpr int Bg  = 1024;          // graphs
constexpr int Sg  = 64;            // nodes per graph
constexpr int EPG = 256;           // edges per graph
constexpr int Nn  = Bg * Sg;       // 65536 nodes
constexpr int Ne  = Bg * EPG;      // 262144 edges
constexpr int NH  = 4;             // attention heads
constexpr float NEG = 0.2f;

constexpr int CHUNK_G = 512;               // graphs per GAT-layer chunk
constexpr int CHUNK_N = CHUNK_G * Sg;      // 32768 nodes

typedef float  f32x4  __attribute__((ext_vector_type(4)));
typedef short  s16x8  __attribute__((ext_vector_type(8)));
typedef unsigned short u16x4 __attribute__((ext_vector_type(4)));

static __device__ __forceinline__ unsigned fenc(float f) {
    unsigned u = __float_as_uint(f);
    return (u & 0x80000000u) ? ~u : (u | 0x80000000u);
}
static __device__ __forceinline__ float fdec(unsigned k) {
    unsigned u = (k & 0x80000000u) ? (k ^ 0x80000000u) : ~k;
    return __uint_as_float(u);
}
static __device__ __forceinline__ unsigned short bf16rn(float x) {
    unsigned u = __float_as_uint(x);
    u += 0x7FFFu + ((u >> 16) & 1u);
    return (unsigned short)(u >> 16);
}
static __device__ __forceinline__ float bf16f(unsigned short h) {
    return __uint_as_float((unsigned)h << 16);
}
// pack fp32 -> (bf16 hi | bf16 lo) in one u32; hi+lo reconstructs x to ~2^-17 rel
static __device__ __forceinline__ unsigned pack32(float x) {
    unsigned u  = __float_as_uint(x);
    unsigned hb = u & 0xffff0000u;
    float lof   = x - __uint_as_float(hb);
    return hb | (__float_as_uint(lof) >> 16);
}
static __device__ __forceinline__ float up_hi(unsigned u) {
    return __uint_as_float(u & 0xffff0000u);
}
static __device__ __forceinline__ float up_lo(unsigned u) {
    return __uint_as_float(u << 16);
}
static __device__ __forceinline__ float unpk(unsigned u) {
    return up_hi(u) + up_lo(u);
}
// relu on packed bf16x2: sign(value)==sign(hi)==bit31
static __device__ __forceinline__ unsigned relu_pk(unsigned u) {
    return ((int)u < 0) ? 0u : u;
}
// column swizzle for the x-tiles: spreads the B-gather's lg groups across banks
#define SWZ(r) (((((r) >> 3) & 1) << 4) | ((((r) >> 3) & 2) << 1))
// wave64 sum via DPP: row_shr 1,2,4,8 then row_bcast 15,31; total lands in lane 63
#define DPP_ADD(x, ctrl) \
    ((x) + __int_as_float(__builtin_amdgcn_update_dpp( \
        0, __float_as_int(x), (ctrl), 0xF, 0xF, true)))

// ---------------- weight prep: transpose + hi/lo bf16 split ----------------
__global__ __launch_bounds__(256)
void wprep(const float* __restrict__ gWl, const float* __restrict__ gWr,
           const float* __restrict__ Wq, const float* __restrict__ Wk,
           const float* __restrict__ Wv, const float* __restrict__ Wo,
           unsigned short* __restrict__ whi, unsigned short* __restrict__ wlo) {
    int gid = blockIdx.x, t = threadIdx.x;
    const float* src;
    int n, k;
    size_t oidx;
    if (gid < 1536) {
        int s = gid >> 8;
        int e = ((gid & 255) << 8) + t;
        n = e & 511; k = e >> 9;
        src = (s & 1) ? (gWr + (s >> 1) * 65536) : (gWl + (s >> 1) * 65536);
        oidx = (size_t)s * 65536 + n * 128 + k;
        float v = src[k * 512 + n];
        unsigned short h = bf16rn(v);
        whi[oidx] = h;
        wlo[oidx] = bf16rn(v - bf16f(h));
    } else {
        int g2 = gid - 1536;
        int s = g2 >> 6;
        int e = ((g2 & 63) << 8) + t;
        n = e & 127; k = e >> 7;
        src = (s == 0) ? Wq : (s == 1) ? Wk : (s == 2) ? Wv : Wo;
        oidx = 393216 + (size_t)s * 16384 + n * 128 + k;
        float v = src[k * 128 + n];
        unsigned short h = bf16rn(v);
        whi[oidx] = h;
        wlo[oidx] = bf16rn(v - bf16f(h));
    }
}

// ---------------- layer-0 projections (K=9), packed output ----------------
__global__ __launch_bounds__(256)
void proj0(const float* __restrict__ x, const float* __restrict__ Wl,
           const float* __restrict__ Wr, const float* __restrict__ bl,
           const float* __restrict__ br, unsigned* __restrict__ xl0,
           unsigned* __restrict__ xr0) {
    int t = blockIdx.x * 256 + threadIdx.x;     // Nn*128 threads
    int n = t >> 7, j = t & 127;
    float xv[9];
#pragma unroll
    for (int k = 0; k < 9; ++k) xv[k] = x[n * 9 + k];
    float al = bl[j], ar = br[j];
#pragma unroll
    for (int k = 0; k < 9; ++k) {
        al = fmaf(xv[k], Wl[k * 128 + j], al);
        ar = fmaf(xv[k], Wr[k * 128 + j], ar);
    }
    xl0[t] = pack32(al);
    xr0[t] = pack32(ar);
}

// ---------------- bf16x3 MFMA GEMM, K=128, 128x128 tile ----------------
// IN_MODE: 0 = plain fp32 A; 1 = packed A; 2 = packed A + relu
// OUT_MODE: 0 = packed out (+bias); 1 = plain out (+bias);
//           2 = plain out = (acc + bias + unpk(hres)) * 0.5
template<int IN_MODE, int OUT_MODE>
__global__ __launch_bounds__(256, 2)
void gemm_mfma(const void* __restrict__ Av, const unsigned short* __restrict__ wth,
               const unsigned short* __restrict__ wtl, const float* __restrict__ bias,
               const unsigned* __restrict__ hres, void* __restrict__ Cv, int NC) {
    __shared__ __align__(16) char smem[65536];
    constexpr int AH = 0, AL = 16384, BH = 32768, BL = 49152;

    const int t = threadIdx.x;
    const int r0 = blockIdx.y * 128, c0 = blockIdx.x * 128;
    const int wave = t >> 6, lane = t & 63;
    const int wm = wave >> 1, wn = wave & 1;
    const int lr = lane & 15, lg = lane >> 4;

    f32x4 acc[4][4] = {};

    int rowA[4], rowB[4];
#pragma unroll
    for (int i = 0; i < 4; ++i) {
        rowA[i] = wm * 64 + i * 16 + lr;
        rowB[i] = wn * 64 + i * 16 + lr;
    }

    for (int kc = 0; kc < 2; ++kc) {
        // ---- stage A ----
#pragma unroll
        for (int i = 0; i < 8; ++i) {
            int f = t + i * 256;
            int row = f >> 4;
            int c4  = (f & 15) << 2;
            u16x4 hp, lp;
            if (IN_MODE == 0) {
                float4 v = *reinterpret_cast<const float4*>(
                    &((const float*)Av)[(size_t)(r0 + row) * 128 + kc * 64 + c4]);
                unsigned short h0 = bf16rn(v.x), h1 = bf16rn(v.y),
                               h2 = bf16rn(v.z), h3 = bf16rn(v.w);
                hp = u16x4{h0, h1, h2, h3};
                lp = u16x4{bf16rn(v.x - bf16f(h0)), bf16rn(v.y - bf16f(h1)),
                           bf16rn(v.z - bf16f(h2)), bf16rn(v.w - bf16f(h3))};
            } else {
                uint4 u = *reinterpret_cast<const uint4*>(
                    &((const unsigned*)Av)[(size_t)(r0 + row) * 128 + kc * 64 + c4]);
                if (IN_MODE == 2) {
                    u.x = relu_pk(u.x); u.y = relu_pk(u.y);
                    u.z = relu_pk(u.z); u.w = relu_pk(u.w);
                }
                hp = u16x4{(unsigned short)(u.x >> 16), (unsigned short)(u.y >> 16),
                           (unsigned short)(u.z >> 16), (unsigned short)(u.w >> 16)};
                lp = u16x4{(unsigned short)(u.x & 0xffffu), (unsigned short)(u.y & 0xffffu),
                           (unsigned short)(u.z & 0xffffu), (unsigned short)(u.w & 0xffffu)};
            }
            int off = row * 128 + ((c4 * 2) ^ ((row & 7) << 4));
            *reinterpret_cast<u16x4*>(smem + AH + off) = hp;
            *reinterpret_cast<u16x4*>(smem + AL + off) = lp;
        }
        // ---- stage B ----
#pragma unroll
        for (int i = 0; i < 4; ++i) {
            int f = t + i * 256;
            int row = f >> 3;
            int c8  = (f & 7) << 3;
            size_t gsrc = (size_t)(c0 + row) * 128 + kc * 64 + c8;
            s16x8 hv = *reinterpret_cast<const s16x8*>(&wth[gsrc]);
            s16x8 lv = *reinterpret_cast<const s16x8*>(&wtl[gsrc]);
            int off = row * 128 + ((c8 * 2) ^ ((row & 7) << 4));
            *reinterpret_cast<s16x8*>(smem + BH + off) = hv;
            *reinterpret_cast<s16x8*>(smem + BL + off) = lv;
        }
        __syncthreads();

#pragma unroll
        for (int ks = 0; ks < 2; ++ks) {
            const int kb = ks * 64 + lg * 16;
            s16x8 ah[4], al4[4];
#pragma unroll
            for (int mi = 0; mi < 4; ++mi) {
                int off = rowA[mi] * 128 + (kb ^ ((rowA[mi] & 7) << 4));
                ah[mi]  = *reinterpret_cast<const s16x8*>(smem + AH + off);
                al4[mi] = *reinterpret_cast<const s16x8*>(smem + AL + off);
            }
#pragma unroll
            for (int ni = 0; ni < 4; ++ni) {
                int off = rowB[ni] * 128 + (kb ^ ((rowB[ni] & 7) << 4));
                s16x8 bh = *reinterpret_cast<const s16x8*>(smem + BH + off);
                s16x8 bl = *reinterpret_cast<const s16x8*>(smem + BL + off);
#pragma unroll
                for (int mi = 0; mi < 4; ++mi) {
                    acc[mi][ni] = __builtin_amdgcn_mfma_f32_16x16x32_bf16(
                        ah[mi], bh, acc[mi][ni], 0, 0, 0);
                    acc[mi][ni] = __builtin_amdgcn_mfma_f32_16x16x32_bf16(
                        ah[mi], bl, acc[mi][ni], 0, 0, 0);
                    acc[mi][ni] = __builtin_amdgcn_mfma_f32_16x16x32_bf16(
                        al4[mi], bh, acc[mi][ni], 0, 0, 0);
                }
            }
        }
        __syncthreads();
    }

#pragma unroll
    for (int ni = 0; ni < 4; ++ni) {
        int c = c0 + wn * 64 + ni * 16 + lr;
        float bs = bias[c];
#pragma unroll
        for (int mi = 0; mi < 4; ++mi) {
#pragma unroll
            for (int j = 0; j < 4; ++j) {
                int r = r0 + wm * 64 + mi * 16 + lg * 4 + j;
                float ov = acc[mi][ni][j] + bs;
                if (OUT_MODE == 0) {
                    ((unsigned*)Cv)[(size_t)r * NC + c] = pack32(ov);
                } else if (OUT_MODE == 1) {
                    ((float*)Cv)[(size_t)r * NC + c] = ov;
                } else {
                    ov = (ov + unpk(hres[(size_t)r * 128 + c])) * 0.5f;
                    ((float*)Cv)[(size_t)r * NC + c] = ov;
                }
            }
        }
    }
}

// ---------------- GATv2 edge kernel v4: packed IO, swizzled tiles ----------------
template<int HEADS, int EPI>
__global__ __launch_bounds__(512, 4)
void gat_edge(const unsigned* __restrict__ xl, const unsigned* __restrict__ xr,
              const int* __restrict__ ei, const float* __restrict__ ea,
              const float* __restrict__ We, const float* __restrict__ att,
              const float* __restrict__ bias, const unsigned* __restrict__ hres,
              unsigned* __restrict__ hout, int g0) {
    constexpr int WROW = HEADS * 128;
    __shared__ __align__(16) unsigned xli[64 * 128];   // packed xl tile, col-swizzled
    __shared__ __align__(16) unsigned xri[64 * 128];   // packed xr tile; P32 alias
    __shared__ float eas[EPG * 4];
    __shared__ float logit[EPG];
    __shared__ int   se[EPG], de[EPG];
    __shared__ unsigned nmax[64];
    __shared__ float nden[64];

    const int g = g0 + blockIdx.x;
    const int t = threadIdx.x, lane = t & 63, wave = t >> 6;   // 8 waves
    const int lr = lane & 15, lg = lane >> 4;
    const int wm = wave >> 2, wn = wave & 3;    // 2 (dst-half) x 4 (dim-quarter)
    const int swzB = ((lg & 1) << 4) | ((lg & 2) << 1);   // == SWZ of gathered rows

    if (t < EPG) {
        se[t] = ei[g * EPG + t] - g * 64;
        de[t] = ei[Ne + g * EPG + t] - g * 64;
        eas[t * 4 + 0] = ea[(size_t)(g * EPG + t) * 3 + 0];
        eas[t * 4 + 1] = ea[(size_t)(g * EPG + t) * 3 + 1];
        eas[t * 4 + 2] = ea[(size_t)(g * EPG + t) * 3 + 2];
    }

    f32x4 acc[2][2] = {};
    float* P32 = reinterpret_cast<float*>(xri);

    for (int hh = 0; hh < HEADS; ++hh) {
        __syncthreads();   // prev head's MFMA done with xli / P32
        // ---- stage packed tiles (pure copy, swizzled columns) ----
#pragma unroll
        for (int i = 0; i < 4; ++i) {
            int f  = t + i * 512;                 // 2048 uint4
            int r  = f >> 5;
            int c4 = (f & 31) << 2;
            size_t nl = (size_t)((g - g0) * 64 + r);
            uint4 pl = *reinterpret_cast<const uint4*>(&xl[nl * WROW + hh * 128 + c4]);
            uint4 pr = *reinterpret_cast<const uint4*>(&xr[nl * WROW + hh * 128 + c4]);
            int cs = c4 ^ SWZ(r);
            *reinterpret_cast<uint4*>(&xli[r * 128 + cs]) = pl;
            *reinterpret_cast<uint4*>(&xri[r * 128 + cs]) = pr;
        }
        if (t < 64) { nmax[t] = 0u; nden[t] = 0.f; }
        __syncthreads();

        // per-lane constants: this lane owns dims 2*lane, 2*lane+1
        const float a1 = att[hh * 128 + 2 * lane];
        const float a2 = att[hh * 128 + 2 * lane + 1];
        float we1[3], we2[3];
#pragma unroll
        for (int k = 0; k < 3; ++k) {
            we1[k] = We[k * WROW + hh * 128 + 2 * lane];
            we2[k] = We[k * WROW + hh * 128 + 2 * lane + 1];
        }

        // ---- logits: b64 gather + DPP wave-reduce ----
        for (int e = wave; e < EPG; e += 8) {
            int s_ = se[e], d_ = de[e];
            float4 ev = *reinterpret_cast<const float4*>(&eas[e * 4]);
            uint2 ul = *reinterpret_cast<const uint2*>(
                &xli[s_ * 128 + ((2 * lane) ^ SWZ(s_))]);
            uint2 ur = *reinterpret_cast<const uint2*>(
                &xri[d_ * 128 + ((2 * lane) ^ SWZ(d_))]);
            float m1 = unpk(ul.x) + unpk(ur.x)
                       + ev.x * we1[0] + ev.y * we1[1] + ev.z * we1[2];
            float m2 = unpk(ul.y) + unpk(ur.y)
                       + ev.x * we2[0] + ev.y * we2[1] + ev.z * we2[2];
            m1 = m1 > 0.f ? m1 : NEG * m1;
            m2 = m2 > 0.f ? m2 : NEG * m2;
            float r = fmaf(m1, a1, m2 * a2);
            r = DPP_ADD(r, 0x111);   // row_shr:1
            r = DPP_ADD(r, 0x112);   // row_shr:2
            r = DPP_ADD(r, 0x114);   // row_shr:4
            r = DPP_ADD(r, 0x118);   // row_shr:8
            r = DPP_ADD(r, 0x142);   // row_bcast:15
            r = DPP_ADD(r, 0x143);   // row_bcast:31 -> lane63 = total
            if (lane == 63) logit[e] = r;
        }
        __syncthreads();

        // ---- segment softmax; xr tile dead -> P32[dst][src] stride 68 ----
        for (int i = t; i < 1088; i += 512)
            reinterpret_cast<float4*>(P32)[i] = float4{0.f, 0.f, 0.f, 0.f};
        if (t < EPG) atomicMax(&nmax[de[t]], fenc(logit[t]));
        __syncthreads();
        float ex = 0.f;
        if (t < EPG) {
            ex = __expf(logit[t] - fdec(nmax[de[t]]));
            atomicAdd(&nden[de[t]], ex);
        }
        __syncthreads();
        if (t < EPG) atomicAdd(&P32[de[t] * 68 + se[t]], ex / nden[de[t]]);
        __syncthreads();

        // ---- MFMA P@X ----
#pragma unroll
        for (int ks = 0; ks < 2; ++ks) {
            s16x8 bh[2], bl[2];
#pragma unroll
            for (int nt = 0; nt < 2; ++nt) {
                int n = (wn * 32 + nt * 16 + lr) ^ swzB;
                unsigned uu[8];
#pragma unroll
                for (int j = 0; j < 8; ++j)
                    uu[j] = xli[(ks * 32 + lg * 8 + j) * 128 + n];
#pragma unroll
                for (int j = 0; j < 8; ++j) {
                    bh[nt][j] = (short)(uu[j] >> 16);
                    bl[nt][j] = (short)(uu[j] & 0xffffu);
                }
            }
#pragma unroll
            for (int mi = 0; mi < 2; ++mi) {
                const float* pr = &P32[(wm * 32 + mi * 16 + lr) * 68 + ks * 32 + lg * 8];
                float4 p0 = *reinterpret_cast<const float4*>(pr);
                float4 p1 = *reinterpret_cast<const float4*>(pr + 4);
                float pv[8] = {p0.x, p0.y, p0.z, p0.w, p1.x, p1.y, p1.z, p1.w};
                s16x8 pah, pal;
#pragma unroll
                for (int j = 0; j < 8; ++j) {
                    unsigned u = __float_as_uint(pv[j]);
                    unsigned hb = u & 0xffff0000u;
                    pah[j] = (short)(u >> 16);
                    pal[j] = (short)(__float_as_uint(pv[j] - __uint_as_float(hb)) >> 16);
                }
#pragma unroll
                for (int nt = 0; nt < 2; ++nt) {
                    acc[mi][nt] = __builtin_amdgcn_mfma_f32_16x16x32_bf16(
                        pah, bh[nt], acc[mi][nt], 0, 0, 0);
                    acc[mi][nt] = __builtin_amdgcn_mfma_f32_16x16x32_bf16(
                        pah, bl[nt], acc[mi][nt], 0, 0, 0);
                    acc[mi][nt] = __builtin_amdgcn_mfma_f32_16x16x32_bf16(
                        pal, bh[nt], acc[mi][nt], 0, 0, 0);
                }
            }
        }
    }

    // ---- epilogue: col=lr, row=lg*4+j per frag; packed output ----
    constexpr float inv = 1.0f / (float)HEADS;
#pragma unroll
    for (int mi = 0; mi < 2; ++mi) {
#pragma unroll
        for (int nt = 0; nt < 2; ++nt) {
            int c_ = wn * 32 + nt * 16 + lr;
            float bs = bias[c_];
#pragma unroll
            for (int j = 0; j < 4; ++j) {
                int r_ = wm * 32 + mi * 16 + lg * 4 + j;
                size_t gi = (size_t)(g * 64 + r_) * 128 + c_;
                float v = acc[mi][nt][j] * inv + bs;
                if (EPI == 1) v = (v + unpk(hres[gi])) * 0.5f;
                hout[gi] = pack32(v);
            }
        }
    }
}

// ---------------- dense attention: one block per (graph, head) ----------------
__global__ __launch_bounds__(256, 3)
void attn_k(const float* __restrict__ q, const float* __restrict__ k,
            const float* __restrict__ v, float* __restrict__ o) {
    __shared__ __align__(16) float qT[32 * 68];
    __shared__ __align__(16) float kT[32 * 68];
    __shared__ __align__(16) float vs[64 * 36];
    __shared__ __align__(16) float St[64 * 68];
    __shared__ float rden[64];

    const int g = blockIdx.x >> 2, hh = blockIdx.x & 3;
    const int t = threadIdx.x;

#pragma unroll
    for (int i = 0; i < 2; ++i) {
        int f = t + i * 256;
        int row = f >> 3;
        int c4  = (f & 7) << 2;
        size_t gi = (size_t)(g * 64 + row) * 128 + hh * 32 + c4;
        float4 qv = *reinterpret_cast<const float4*>(&q[gi]);
        float4 kv = *reinterpret_cast<const float4*>(&k[gi]);
        float4 vv = *reinterpret_cast<const float4*>(&v[gi]);
        qT[(c4 + 0) * 68 + row] = qv.x; qT[(c4 + 1) * 68 + row] = qv.y;
        qT[(c4 + 2) * 68 + row] = qv.z; qT[(c4 + 3) * 68 + row] = qv.w;
        kT[(c4 + 0) * 68 + row] = kv.x; kT[(c4 + 1) * 68 + row] = kv.y;
        kT[(c4 + 2) * 68 + row] = kv.z; kT[(c4 + 3) * 68 + row] = kv.w;
        *reinterpret_cast<float4*>(&vs[row * 36 + c4]) = vv;
    }
    __syncthreads();

    {
        const int rg = (t & 15) << 2, cg = (t >> 4) << 2;
        float acc[4][4] = {};
#pragma unroll 8
        for (int kk = 0; kk < 32; ++kk) {
            float4 qv = *reinterpret_cast<const float4*>(&qT[kk * 68 + rg]);
            float4 kv = *reinterpret_cast<const float4*>(&kT[kk * 68 + cg]);
            acc[0][0] = fmaf(qv.x, kv.x, acc[0][0]);
            acc[0][1] = fmaf(qv.x, kv.y, acc[0][1]);
            acc[0][2] = fmaf(qv.x, kv.z, acc[0][2]);
            acc[0][3] = fmaf(qv.x, kv.w, acc[0][3]);
            acc[1][0] = fmaf(qv.y, kv.x, acc[1][0]);
            acc[1][1] = fmaf(qv.y, kv.y, acc[1][1]);
            acc[1][2] = fmaf(qv.y, kv.z, acc[1][2]);
            acc[1][3] = fmaf(qv.y, kv.w, acc[1][3]);
            acc[2][0] = fmaf(qv.z, kv.x, acc[2][0]);
            acc[2][1] = fmaf(qv.z, kv.y, acc[2][1]);
            acc[2][2] = fmaf(qv.z, kv.z, acc[2][2]);
            acc[2][3] = fmaf(qv.z, kv.w, acc[2][3]);
            acc[3][0] = fmaf(qv.w, kv.x, acc[3][0]);
            acc[3][1] = fmaf(qv.w, kv.y, acc[3][1]);
            acc[3][2] = fmaf(qv.w, kv.z, acc[3][2]);
            acc[3][3] = fmaf(qv.w, kv.w, acc[3][3]);
        }
        constexpr float sc = 0.17677669529663687f;
#pragma unroll
        for (int j = 0; j < 4; ++j) {
            float4 sv;
            sv.x = acc[0][j] * sc; sv.y = acc[1][j] * sc;
            sv.z = acc[2][j] * sc; sv.w = acc[3][j] * sc;
            *reinterpret_cast<float4*>(&St[(cg + j) * 68 + rg]) = sv;
        }
    }
    __syncthreads();

    {
        const int r = t >> 2, q4 = t & 3;
        float mx = -3.4e38f;
#pragma unroll
        for (int i = 0; i < 16; ++i)
            mx = fmaxf(mx, St[(q4 * 16 + i) * 68 + r]);
        mx = fmaxf(mx, __shfl_xor(mx, 1, 64));
        mx = fmaxf(mx, __shfl_xor(mx, 2, 64));
        float sm = 0.f;
#pragma unroll
        for (int i = 0; i < 16; ++i) {
            int idx = (q4 * 16 + i) * 68 + r;
            float e = __expf(St[idx] - mx);
            St[idx] = e;
            sm += e;
        }
        sm += __shfl_xor(sm, 1, 64);
        sm += __shfl_xor(sm, 2, 64);
        if (q4 == 0) rden[r] = 1.f / sm;
    }
    __syncthreads();

    {
        const int rg = (t & 15) << 2, dg = (t >> 4) << 1;
        float a0 = 0.f, a1 = 0.f, a2 = 0.f, a3 = 0.f;
        float b0 = 0.f, b1 = 0.f, b2 = 0.f, b3 = 0.f;
#pragma unroll 8
        for (int kk = 0; kk < 64; ++kk) {
            float4 pv = *reinterpret_cast<const float4*>(&St[kk * 68 + rg]);
            float2 vv = *reinterpret_cast<const float2*>(&vs[kk * 36 + dg]);
            a0 = fmaf(pv.x, vv.x, a0); b0 = fmaf(pv.x, vv.y, b0);
            a1 = fmaf(pv.y, vv.x, a1); b1 = fmaf(pv.y, vv.y, b1);
            a2 = fmaf(pv.z, vv.x, a2); b2 = fmaf(pv.z, vv.y, b2);
            a3 = fmaf(pv.w, vv.x, a3); b3 = fmaf(pv.w, vv.y, b3);
        }
        float4 rd = *reinterpret_cast<const float4*>(&rden[rg]);
        float2 o0 = {a0 * rd.x, b0 * rd.x};
        float2 o1 = {a1 * rd.y, b1 * rd.y};
        float2 o2 = {a2 * rd.z, b2 * rd.z};
        float2 o3 = {a3 * rd.w, b3 * rd.w};
        size_t gb = (size_t)(g * 64 + rg) * 128 + hh * 32 + dg;
        *reinterpret_cast<float2*>(&o[gb])       = o0;
        *reinterpret_cast<float2*>(&o[gb + 128]) = o1;
        *reinterpret_cast<float2*>(&o[gb + 256]) = o2;
        *reinterpret_cast<float2*>(&o[gb + 384]) = o3;
    }
}

// ---------------- launch ----------------
extern "C" void kernel_launch(void* const* d_in, const int* in_sizes, int n_in,
                              void* d_out, int out_size, void* d_ws, size_t ws_size,
                              hipStream_t stream) {
    const float* x     = (const float*)d_in[0];
    const int*   ei    = (const int*)d_in[1];
    const float* ea    = (const float*)d_in[2];
    const float* g0Wl  = (const float*)d_in[4];
    const float* g0Wr  = (const float*)d_in[5];
    const float* g0bl  = (const float*)d_in[6];
    const float* g0br  = (const float*)d_in[7];
    const float* g0We  = (const float*)d_in[8];
    const float* g0att = (const float*)d_in[9];
    const float* g0bias= (const float*)d_in[10];
    const float* gWl   = (const float*)d_in[11];
    const float* gWr   = (const float*)d_in[12];
    const float* gbl   = (const float*)d_in[13];
    const float* gbr   = (const float*)d_in[14];
    const float* gWe   = (const float*)d_in[15];
    const float* gatt  = (const float*)d_in[16];
    const float* gbias = (const float*)d_in[17];
    const float* Wq    = (const float*)d_in[18];
    const float* Wk    = (const float*)d_in[19];
    const float* Wv    = (const float*)d_in[20];
    const float* bq    = (const float*)d_in[21];
    const float* bk    = (const float*)d_in[22];
    const float* bv    = (const float*)d_in[23];
    const float* Wo    = (const float*)d_in[24];
    const float* bo    = (const float*)d_in[25];
    float* out = (float*)d_out;

    unsigned* h   = (unsigned*)d_ws;                       // Nn*128 packed
    unsigned* xlb = h + (size_t)Nn * 128;                  // CHUNK_N*512 packed
    unsigned* xrb = xlb + (size_t)CHUNK_N * 512;           // CHUNK_N*512 packed
    float* qb = (float*)xlb;
    float* kb = (float*)(xlb + (size_t)Nn * 128);
    float* vb = (float*)xrb;
    float* ob = (float*)(xrb + (size_t)Nn * 128);
    unsigned short* whi = (unsigned short*)(xrb + (size_t)CHUNK_N * 512);
    unsigned short* wlo = whi + 458752;

    wprep<<<1792, 256, 0, stream>>>(gWl, gWr, Wq, Wk, Wv, Wo, whi, wlo);

    // ---- layer 0 (heads=1, concat) ----
    proj0<<<Nn * 128 / 256, 256, 0, stream>>>(x, g0Wl, g0Wr, g0bl, g0br, xlb, xrb);
    gat_edge<1, 0><<<Bg, 512, 0, stream>>>(xlb, xrb, ei, ea, g0We, g0att,
                                           g0bias, nullptr, h, 0);

    // ---- layers 1..3 (heads=4, mean, residual) ----
    for (int i = 0; i < 3; ++i) {
        for (int c = 0; c < 2; ++c) {
            const unsigned* Ain = h + (size_t)c * CHUNK_N * 128;
            dim3 grid(512 / 128, CHUNK_N / 128);
            gemm_mfma<2, 0><<<grid, 256, 0, stream>>>(
                Ain, whi + (size_t)(2 * i) * 65536, wlo + (size_t)(2 * i) * 65536,
                gbl + i * 512, nullptr, xlb, 512);
            gemm_mfma<2, 0><<<grid, 256, 0, stream>>>(
                Ain, whi + (size_t)(2 * i + 1) * 65536, wlo + (size_t)(2 * i + 1) * 65536,
                gbr + i * 512, nullptr, xrb, 512);
            gat_edge<4, 1><<<CHUNK_G, 512, 0, stream>>>(
                xlb, xrb, ei, ea, gWe + (size_t)i * 3 * 512,
                gatt + (size_t)i * 4 * 128, gbias + i * 128, h, h, c * CHUNK_G);
        }
    }

    // ---- dense attention over graphs ----
    {
        dim3 grid(1, Nn / 128);
        gemm_mfma<1, 1><<<grid, 256, 0, stream>>>(h, whi + 393216, wlo + 393216,
                                                  bq, nullptr, qb, 128);
        gemm_mfma<1, 1><<<grid, 256, 0, stream>>>(h, whi + 409600, wlo + 409600,
                                                  bk, nullptr, kb, 128);
        gemm_mfma<1, 1><<<grid, 256, 0, stream>>>(h, whi + 425984, wlo + 425984,
                                                  bv, nullptr, vb, 128);
        attn_k<<<Bg * NH, 256, 0, stream>>>(qb, kb, vb, ob);
        gemm_mfma<0, 2><<<grid, 256, 0, stream>>>(ob, whi + 442368, wlo + 442368,
                                                  bo, h, out, 128);
    }
}